// Round 12
// baseline (379.289 us; speedup 1.0000x reference)
//
#include <hip/hip_runtime.h>
#include <stdint.h>

#define D_FEAT   128
#define TOPK     128
#define KSPLIT   384           // 3 x 128 (h|h|l) . (h|l|h)
#define SCALE    4096.0f
#define SCALE2   16777216.0f   // SCALE^2 (2^24, exact)
#define SEL_CAP  8192          // per-query candidate capacity
#define SAMPLE_N 1024
#define SAMPLE_R 24

typedef float    f32x4 __attribute__((ext_vector_type(4)));
typedef _Float16 half8 __attribute__((ext_vector_type(8)));

// ---------------- fused prep: sqnorm + f16 (hi,lo) split, one pass ----------------
// One wave per row; lane l handles elems l and l+64.
__global__ __launch_bounds__(256) void prep_kernel(
        const float* __restrict__ Q, const float* __restrict__ Dta,
        unsigned short* __restrict__ Asp, unsigned short* __restrict__ Bsp,
        float* __restrict__ x2, float* __restrict__ y2, int nQ, int nD) {
    int wid  = blockIdx.x * 4 + (threadIdx.x >> 6);
    int lane = threadIdx.x & 63;
    const float* src; unsigned short* dst; float* nrm; int row; int isA;
    if (wid < nQ) { isA = 1; row = wid; src = Q; dst = Asp; nrm = x2; }
    else {
        row = wid - nQ;
        if (row >= nD) return;
        isA = 0; src = Dta; dst = Bsp; nrm = y2;
    }
    float a0 = src[(size_t)row * D_FEAT + lane];
    float a1 = src[(size_t)row * D_FEAT + 64 + lane];
    float s = a0 * a0 + a1 * a1;
    #pragma unroll
    for (int off = 32; off > 0; off >>= 1) s += __shfl_down(s, off, 64);
    if (lane == 0) nrm[row] = s;

    size_t b = (size_t)row * KSPLIT;
    #pragma unroll
    for (int e = 0; e < 2; ++e) {
        float a = (e == 0 ? a0 : a1) * SCALE;
        int   k = lane + e * 64;
        _Float16 h = (_Float16)a;
        float hf = (float)h;
        _Float16 l = (_Float16)(a - hf);
        unsigned short hu, lu;
        __builtin_memcpy(&hu, &h, 2);
        __builtin_memcpy(&lu, &l, 2);
        dst[b + k]              = hu;
        dst[b + D_FEAT + k]     = isA ? hu : lu;
        dst[b + 2 * D_FEAT + k] = isA ? lu : hu;
    }
}

// ---------------- MFMA distance kernel (256x256 tile, 3-buf pipeline) ----------------
// MODE 0: write key16s to keyout (prepass on sample columns)
// MODE 1: filter vs Tq[row], append candidates (key16<<16 | j) to candbuf
#define BM 256
#define BN 256
#define BKS 32
#define NSLAB (KSPLIT / BKS)   // 12
#define ASLOT (BM * 4)         // 1024 16B-slots
#define BSLOT (BN * 4)         // 1024 16B-slots
#define BUFELEM ((ASLOT + BSLOT) * 8)   // u16 per buffer (16384 = 32 KB)

static __device__ __forceinline__ half8 lds_read_half8(const unsigned short* p) {
    half8 r;
    __builtin_memcpy(&r, p, 16);
    return r;
}

static __device__ __forceinline__ void gload_lds16(const unsigned short* g, unsigned short* l) {
    __builtin_amdgcn_global_load_lds(
        (const __attribute__((address_space(1))) unsigned int*)g,
        (__attribute__((address_space(3))) unsigned int*)l, 16, 0, 0);
}

// stage one BK=32 slab: exactly 4 gload_lds per thread (vmcnt +4 per wave).
static __device__ __forceinline__ void stage_slab(
        const unsigned short* __restrict__ Asp,
        const unsigned short* __restrict__ Bsp,
        unsigned short* buf, int aRowBase, int bRowBase, int kt, int w, int l) {
    #pragma unroll
    for (int r = 0; r < 2; ++r) {   // A: 1024 slots, 2 wave-rounds
        int slot = r * 512 + w * 64 + l;
        int row = slot >> 2, c = slot & 3;
        int sc  = c ^ ((row >> 1) & 3);
        gload_lds16(Asp + (size_t)(aRowBase + row) * KSPLIT + kt + sc * 8,
                    buf + (size_t)(r * 512 + w * 64) * 8);
    }
    #pragma unroll
    for (int r = 0; r < 2; ++r) {   // B: 1024 slots, 2 wave-rounds
        int slot = r * 512 + w * 64 + l;
        int row = slot >> 2, c = slot & 3;
        int sc  = c ^ ((row >> 1) & 3);
        gload_lds16(Bsp + (size_t)(bRowBase + row) * KSPLIT + kt + sc * 8,
                    buf + (size_t)(ASLOT + r * 512 + w * 64) * 8);
    }
}

template<int MODE>
__global__ __launch_bounds__(512, 2) void dist_mfma_kernel(
        const unsigned short* __restrict__ Asp,   // [n][384]
        const unsigned short* __restrict__ Bsp,   // [N][384]
        const float* __restrict__ x2,
        const float* __restrict__ y2,
        unsigned short* __restrict__ keyout,      // MODE 0: [n][N]
        const unsigned int* __restrict__ Tq,      // MODE 1
        unsigned int* __restrict__ cnt,           // MODE 1
        unsigned int* __restrict__ candbuf,       // MODE 1
        int N, int rowsM) {
    __shared__ __align__(16) unsigned short sh[3 * BUFELEM];   // 96 KB
    unsigned short* b0 = sh;
    unsigned short* b1 = sh + BUFELEM;
    unsigned short* b2 = sh + 2 * BUFELEM;

    const int nwg = (N / BN) * rowsM;
    const int cpx = nwg >> 3;
    const int bid = blockIdx.x;
    const int swz = (bid & 7) * cpx + (bid >> 3);
    const int col   = swz / rowsM;
    const int mrowi = swz - col * rowsM;
    const int nb = col * BN;
    const int mb = mrowi * BM;

    const int tid  = threadIdx.x;
    const int lane = tid & 63;
    const int w    = tid >> 6;
    const int wr   = w >> 1, wc = w & 1;   // 4 x 2 wave grid: 64 rows x 128 cols each

    f32x4 acc[4][8];
    #pragma unroll
    for (int i = 0; i < 4; ++i)
        #pragma unroll
        for (int j = 0; j < 8; ++j)
            acc[i][j] = (f32x4){0.f, 0.f, 0.f, 0.f};

    // prologue: 2 slabs in flight (8 outstanding loads/wave)
    stage_slab(Asp, Bsp, b0, mb, nb, 0, w, lane);
    stage_slab(Asp, Bsp, b1, mb, nb, BKS, w, lane);

    unsigned short* cur = b0;
    unsigned short* nx1 = b1;
    unsigned short* nx2 = b2;

    const int c = lane >> 4;
    #pragma unroll
    for (int s = 0; s < NSLAB; ++s) {
        if (s < NSLAB - 1) asm volatile("s_waitcnt vmcnt(4)" ::: "memory");
        else               asm volatile("s_waitcnt vmcnt(0)" ::: "memory");
        __builtin_amdgcn_s_barrier();
        asm volatile("" ::: "memory");
        if (s + 2 < NSLAB)
            stage_slab(Asp, Bsp, nx2, mb, nb, (s + 2) * BKS, w, lane);   // overlaps MFMA

        const unsigned short* Acur = cur;
        const unsigned short* Bcur = cur;
        half8 af[4], bf[8];
        #pragma unroll
        for (int f = 0; f < 4; ++f) {
            int m = wr * 64 + f * 16 + (lane & 15);
            af[f] = lds_read_half8(Acur + (size_t)(m * 4 + (c ^ ((m >> 1) & 3))) * 8);
        }
        #pragma unroll
        for (int f = 0; f < 8; ++f) {
            int nn = wc * 128 + f * 16 + (lane & 15);
            bf[f] = lds_read_half8(Bcur + (size_t)(ASLOT + nn * 4 + (c ^ ((nn >> 1) & 3))) * 8);
        }
        __builtin_amdgcn_s_setprio(1);
        #pragma unroll
        for (int i = 0; i < 4; ++i)
            #pragma unroll
            for (int j = 0; j < 8; ++j)
                acc[i][j] = __builtin_amdgcn_mfma_f32_16x16x32_f16(af[i], bf[j], acc[i][j], 0, 0, 0);
        __builtin_amdgcn_s_setprio(0);

        unsigned short* t = cur; cur = nx1; nx1 = nx2; nx2 = t;
    }

    __syncthreads();    // all LDS reads done before epilogue reuse

    float x2v[16];
    unsigned int Trow[16];
    #pragma unroll
    for (int fi = 0; fi < 4; ++fi)
        #pragma unroll
        for (int r = 0; r < 4; ++r) {
            int ml = wr * 64 + fi * 16 + (lane >> 4) * 4 + r;
            x2v[fi * 4 + r] = x2[mb + ml];
            if (MODE == 1) Trow[fi * 4 + r] = Tq[mb + ml];
        }

    if (MODE == 0) {
        #pragma unroll
        for (int fj = 0; fj < 8; ++fj) {
            float yv = y2[nb + wc * 128 + fj * 16 + (lane & 15)];
            #pragma unroll
            for (int fi = 0; fi < 4; ++fi) {
                #pragma unroll
                for (int r = 0; r < 4; ++r) {
                    float d = fmaf(-2.0f, acc[fi][fj][r], SCALE2 * (x2v[fi * 4 + r] + yv));
                    d = fmaxf(d, 0.0f);
                    int m  = mb + wr * 64 + fi * 16 + (lane >> 4) * 4 + r;
                    int nn = nb + wc * 128 + fj * 16 + (lane & 15);
                    keyout[(size_t)m * N + nn] = (unsigned short)(__float_as_uint(d) >> 15);
                }
            }
        }
    } else {
        // per-row LDS hit lists -> one global atomic per (row, block)
        unsigned int* rowcnt  = (unsigned int*)sh;             // 256
        unsigned int* slots   = rowcnt + 256;                  // 256*32
        unsigned int* rowbase = slots + 256 * 32;              // 256
        for (int i = tid; i < 256; i += 512) rowcnt[i] = 0;
        __syncthreads();
        #pragma unroll
        for (int fj = 0; fj < 8; ++fj) {
            float yv = y2[nb + wc * 128 + fj * 16 + (lane & 15)];
            #pragma unroll
            for (int fi = 0; fi < 4; ++fi) {
                #pragma unroll
                for (int r = 0; r < 4; ++r) {
                    float d = fmaf(-2.0f, acc[fi][fj][r], SCALE2 * (x2v[fi * 4 + r] + yv));
                    d = fmaxf(d, 0.0f);
                    unsigned int key = __float_as_uint(d) >> 15;
                    if (key < Trow[fi * 4 + r]) {
                        int ml = wr * 64 + fi * 16 + (lane >> 4) * 4 + r;
                        int cl = wc * 128 + fj * 16 + (lane & 15);
                        unsigned int p = atomicAdd(&rowcnt[ml], 1u);
                        if (p < 32) {
                            slots[ml * 32 + p] = (key << 16) | (unsigned int)cl;
                        } else {   // rare spill: direct global append
                            unsigned int b = atomicAdd(&cnt[mb + ml], 1u);
                            if (b < SEL_CAP)
                                candbuf[(size_t)(mb + ml) * SEL_CAP + b] =
                                    (key << 16) | (unsigned int)(nb + cl);
                        }
                    }
                }
            }
        }
        __syncthreads();
        int ml2 = tid >> 1;                  // 512 threads -> 2 per row
        unsigned int cc = rowcnt[ml2]; if (cc > 32) cc = 32;
        if ((tid & 1) == 0) rowbase[ml2] = atomicAdd(&cnt[mb + ml2], cc);
        __syncthreads();
        unsigned int bse = rowbase[ml2];
        for (unsigned int i = tid & 1; i < cc; i += 2) {
            unsigned int e = slots[ml2 * 32 + i];
            unsigned int dst = bse + i;
            if (dst < SEL_CAP)
                candbuf[(size_t)(mb + ml2) * SEL_CAP + dst] =
                    (e & 0xFFFF0000u) | (unsigned int)(nb + (e & 0x1FFu));
        }
    }
}

// ---------------- per-query threshold from sample keys (also zeroes cnt) ----------------
__global__ __launch_bounds__(256) void tsel_kernel(const unsigned short* __restrict__ skey,
                                                   unsigned int* __restrict__ Tq,
                                                   unsigned int* __restrict__ cnt) {
    __shared__ unsigned int hist[256];
    __shared__ unsigned int binsel, cumsel, losel;
    const int tid = threadIdx.x;
    const int q   = blockIdx.x;
    if (tid == 0) cnt[q] = 0;
    uint2 v = ((const uint2*)(skey + (size_t)q * SAMPLE_N))[tid];   // 4 keys
    unsigned int k0 = v.x & 0xFFFFu, k1 = v.x >> 16;
    unsigned int k2 = v.y & 0xFFFFu, k3 = v.y >> 16;

    hist[tid] = 0;
    __syncthreads();
    atomicAdd(&hist[k0 >> 8], 1u); atomicAdd(&hist[k1 >> 8], 1u);
    atomicAdd(&hist[k2 >> 8], 1u); atomicAdd(&hist[k3 >> 8], 1u);
    __syncthreads();
    if (tid == 0) {
        unsigned int cum = 0;
        for (int b = 0; b < 256; ++b) {
            unsigned int h = hist[b];
            if (cum + h >= SAMPLE_R) { binsel = (unsigned int)b; cumsel = cum; break; }
            cum += h;
        }
    }
    __syncthreads();
    unsigned int bsel = binsel, need = SAMPLE_R - cumsel;
    hist[tid] = 0;
    __syncthreads();
    if ((k0 >> 8) == bsel) atomicAdd(&hist[k0 & 0xFFu], 1u);
    if ((k1 >> 8) == bsel) atomicAdd(&hist[k1 & 0xFFu], 1u);
    if ((k2 >> 8) == bsel) atomicAdd(&hist[k2 & 0xFFu], 1u);
    if ((k3 >> 8) == bsel) atomicAdd(&hist[k3 & 0xFFu], 1u);
    __syncthreads();
    if (tid == 0) {
        unsigned int cum = 0;
        for (int b = 0; b < 256; ++b) {
            cum += hist[b];
            if (cum >= need) { losel = (unsigned int)b; break; }
        }
        Tq[q] = ((bsel << 8) | losel) + 1u;
    }
}

// ---------------- selection + vote over candidate lists ----------------
#define SEL_T   1024
#define TIE_CAP 1024

__global__ __launch_bounds__(SEL_T) void select7_kernel(
        const unsigned int* __restrict__ cnt,
        const unsigned int* __restrict__ candbuf,
        const float* __restrict__ labels,
        const float* __restrict__ Q, const float* __restrict__ Dta,
        int* __restrict__ out, int n_total, int out_size) {
    __shared__ unsigned int cand[SEL_CAP];   // 32 KB
    __shared__ double       cval[TIE_CAP];   // 8 KB
    __shared__ unsigned int ckey[TIE_CAP];   // 4 KB
    __shared__ unsigned int red[2][3][16];
    __shared__ unsigned int tot[2][3];
    __shared__ unsigned int votes_sh, tcnt;

    const int tid = threadIdx.x;
    const int q   = blockIdx.x;

    unsigned int mraw = cnt[q];
    const int m = (int)(mraw < SEL_CAP ? mraw : SEL_CAP);
    for (int i = tid; i < m; i += SEL_T) cand[i] = candbuf[(size_t)q * SEL_CAP + i];
    if (tid == 0) { votes_sh = 0; tcnt = 0; }
    __syncthreads();

    uint32_t lo = 0, hi = 65536, base = 0;
    #pragma unroll 1
    for (int pass = 0; pass < 8; ++pass) {
        uint32_t qs = (hi - lo) >> 2;
        uint32_t p1 = lo + qs, p2 = p1 + qs, p3 = p2 + qs;
        uint32_t c1 = 0, c2 = 0, c3 = 0;
        #pragma unroll
        for (int p = 0; p < 8; ++p) {
            int idx = p * 1024 + tid;
            if (idx < m) {
                uint32_t key = cand[idx] >> 16;
                c1 += (key < p1); c2 += (key < p2); c3 += (key < p3);
            }
        }
        #pragma unroll
        for (int off = 32; off > 0; off >>= 1) {
            c1 += __shfl_down(c1, off, 64);
            c2 += __shfl_down(c2, off, 64);
            c3 += __shfl_down(c3, off, 64);
        }
        int bsel = pass & 1;
        if ((tid & 63) == 0) {
            int ww = tid >> 6;
            red[bsel][0][ww] = c1; red[bsel][1][ww] = c2; red[bsel][2][ww] = c3;
        }
        __syncthreads();
        if (tid < 48) {
            int g = tid >> 4, i = tid & 15;
            unsigned int v = red[bsel][g][i];
            v += __shfl_xor(v, 1, 64);
            v += __shfl_xor(v, 2, 64);
            v += __shfl_xor(v, 4, 64);
            v += __shfl_xor(v, 8, 64);
            if (i == 0) tot[bsel][g] = v;
        }
        __syncthreads();
        uint32_t t1 = tot[bsel][0], t2 = tot[bsel][1], t3 = tot[bsel][2];
        if      (t1 >= TOPK) { hi = p1; }
        else if (t2 >= TOPK) { lo = p1; hi = p2; base = t1; }
        else if (t3 >= TOPK) { lo = p2; hi = p3; base = t2; }
        else                 { lo = p3;          base = t3; }
    }
    const uint32_t tau    = lo;
    const uint32_t t_take = TOPK - base;

    uint32_t votes = 0;
    #pragma unroll 1
    for (int p = 0; p < 8; ++p) {
        int idx = p * 1024 + tid;
        if (idx < m) {
            uint32_t u = cand[idx];
            uint32_t key = u >> 16;
            uint32_t j   = u & 0xFFFFu;
            if (key < tau) {
                votes += (labels[j] > 0.5f) ? 1u : 0u;
            } else if (key == tau) {
                unsigned int lab = (labels[j] > 0.5f) ? 0x80000000u : 0u;
                unsigned int e = atomicAdd(&tcnt, 1u);
                if (e < TIE_CAP) {
                    const float* qp = Q   + (size_t)q * D_FEAT;
                    const float* dp = Dta + (size_t)j * D_FEAT;
                    double sacc = 0.0;
                    for (int k = 0; k < D_FEAT; ++k) {
                        double df = (double)qp[k] - (double)dp[k];
                        sacc = fma(df, df, sacc);
                    }
                    cval[e] = sacc;
                    ckey[e] = j | lab;
                }
            }
        }
    }
    #pragma unroll
    for (int off = 32; off > 0; off >>= 1)
        votes += __shfl_down(votes, off, 64);
    if ((tid & 63) == 0 && votes) atomicAdd(&votes_sh, votes);
    __syncthreads();

    unsigned int mt = tcnt; if (mt > TIE_CAP) mt = TIE_CAP;
    for (unsigned int e = tid; e < mt; e += SEL_T) {
        double       ve = cval[e];
        unsigned int ke = ckey[e];
        unsigned int ie = ke & 0x7FFFFFFFu;
        unsigned int rank = 0;
        for (unsigned int f = 0; f < mt; ++f) {
            double       vf = cval[f];
            unsigned int jf = ckey[f] & 0x7FFFFFFFu;
            rank += (vf < ve || (vf == ve && jf < ie)) ? 1u : 0u;
        }
        if (rank < t_take && (ke & 0x80000000u)) atomicAdd(&votes_sh, 1u);
    }
    __syncthreads();

    if (tid == 0) {
        out[q] = (votes_sh > TOPK / 2) ? 1 : 0;     // 64/64 tie -> class 0
        if (q == 0 && out_size > n_total) out[n_total] = 0;
    }
}

// ---------------- host ----------------
extern "C" void kernel_launch(void* const* d_in, const int* in_sizes, int n_in,
                              void* d_out, int out_size, void* d_ws, size_t ws_size,
                              hipStream_t stream) {
    const float* Q   = (const float*)d_in[0];
    const float* Dta = (const float*)d_in[1];
    const float* L   = (const float*)d_in[2];
    const int n = in_sizes[0] / D_FEAT;    // 2048
    const int N = in_sizes[1] / D_FEAT;    // 65536
    int* out = (int*)d_out;

    char* ws = (char*)d_ws;
    size_t off = 0;
    float* y2 = (float*)(ws + off);          off += (((size_t)N * 4) + 255) & ~(size_t)255;
    float* x2 = (float*)(ws + off);          off += (((size_t)n * 4) + 255) & ~(size_t)255;
    unsigned short* Asp = (unsigned short*)(ws + off); off += (((size_t)n * KSPLIT * 2) + 255) & ~(size_t)255;
    unsigned short* Bsp = (unsigned short*)(ws + off); off += (((size_t)N * KSPLIT * 2) + 255) & ~(size_t)255;
    unsigned short* skey = (unsigned short*)(ws + off); off += (((size_t)n * SAMPLE_N * 2) + 255) & ~(size_t)255;
    unsigned int* Tq  = (unsigned int*)(ws + off);    off += (((size_t)n * 4) + 255) & ~(size_t)255;
    unsigned int* cnt = (unsigned int*)(ws + off);    off += (((size_t)n * 4) + 255) & ~(size_t)255;
    unsigned int* candbuf = (unsigned int*)(ws + off);   // n * SEL_CAP * 4 = 64 MB

    // fused sqnorm+split, one pass over Q and D
    prep_kernel<<<dim3((n + N + 3) / 4), dim3(256), 0, stream>>>(Q, Dta, Asp, Bsp, x2, y2, n, N);

    const int rowsM = n / BM;                         // 8
    dist_mfma_kernel<0><<<dim3((SAMPLE_N / BN) * rowsM), dim3(512), 0, stream>>>(
        Asp, Bsp, x2, y2, skey, nullptr, nullptr, nullptr, SAMPLE_N, rowsM);
    tsel_kernel<<<dim3(n), dim3(256), 0, stream>>>(skey, Tq, cnt);
    dist_mfma_kernel<1><<<dim3((N / BN) * rowsM), dim3(512), 0, stream>>>(
        Asp, Bsp, x2, y2, nullptr, Tq, cnt, candbuf, N, rowsM);
    select7_kernel<<<dim3(n), dim3(SEL_T), 0, stream>>>(cnt, candbuf, L, Q, Dta, out, n, out_size);
}